// Round 1
// baseline (422.677 us; speedup 1.0000x reference)
//
#include <hip/hip_runtime.h>
#include <cstdint>
#include <cstddef>

#define NN 4096
#define CC 256
#define GG 50
#define PB 32
#define JD 384

#define O_OUT1 819200
#define O_OUT2 1638400
#define O_OUT3 68747264
#define O_OUT4 68763648

__device__ __forceinline__ unsigned bf16b(float f) {
    unsigned u = __float_as_uint(f);
    return (u + 0x7FFFu + ((u >> 16) & 1u)) >> 16;   // RNE f32->bf16
}
__device__ __forceinline__ float bf16f(short s) {
    return __uint_as_float(((unsigned)(unsigned short)s) << 16);
}

// ------------- k_proj: per 32 points, compute 384 fp32 proj dims (sim|sem|conf), ----------
// ------------- seg softmax, conf sigmoid, bf16 Fsim to ws, PLUS row norm r=sum(bf16(Fsim)^2)
__global__ __launch_bounds__(256) void k_proj(
    const float* __restrict__ x,
    const float* __restrict__ Wsem, const float* __restrict__ bsem,
    const float* __restrict__ Wseg, const float* __restrict__ bseg,
    const float* __restrict__ Wsim, const float* __restrict__ bsim,
    const float* __restrict__ Wconf, const float* __restrict__ bconf,
    const float* __restrict__ Wcl, const float* __restrict__ bcl,
    unsigned* __restrict__ fsimu, float* __restrict__ rnorm,
    float* __restrict__ out0, float* __restrict__ out1,
    float* __restrict__ out3, float* __restrict__ out4)
{
    __shared__ float smem[15360];          // xs [256][36]=9216 | wch [16][384]=6144
    __shared__ float confl[PB], mxs[PB], sms[PB], rns[PB];

    float* xs  = smem;                     // x tile transposed [k][p], stride 36
    float* wch = smem + 9216;              // weight k-chunk [16][384]

    int t = threadIdx.x;
    int pbase = blockIdx.x * PB;
    if (t < PB) { confl[t] = 0.f; rns[t] = 0.f; }

    #pragma unroll 4
    for (int p = 0; p < PB; ++p)
        xs[t * 36 + p] = x[(size_t)(pbase + p) * CC + t];     // coalesced over t

    int tj = t & 31, tp = t >> 5;          // tj: 32 groups of 12 dims; tp: 8 groups of 4 pts
    float acc[4][12];
    #pragma unroll
    for (int pp = 0; pp < 4; ++pp)
        #pragma unroll
        for (int jj = 0; jj < 12; ++jj) acc[pp][jj] = 0.f;

    for (int kc = 0; kc < 16; ++kc) {
        __syncthreads();
        #pragma unroll
        for (int i = 0; i < 8; ++i) {      // stage 16 x 384 weight chunk (3 matrices)
            int idx = i * 256 + t;
            int k = idx >> 7, jj = idx & 127;
            int g = (kc * 16 + k) * 128 + jj;
            wch[k * JD +       jj] = Wsim[g];
            wch[k * JD + 128 + jj] = Wsem[g];
            wch[k * JD + 256 + jj] = Wconf[g];
        }
        __syncthreads();
        #pragma unroll
        for (int k = 0; k < 16; ++k) {
            const float* xp = &xs[(kc * 16 + k) * 36 + tp * 4];
            float a0 = xp[0], a1 = xp[1], a2 = xp[2], a3 = xp[3];
            const float* wr = &wch[k * JD + tj * 12];
            #pragma unroll
            for (int jj = 0; jj < 12; ++jj) {
                float w = wr[jj];
                acc[0][jj] = fmaf(a0, w, acc[0][jj]);
                acc[1][jj] = fmaf(a1, w, acc[1][jj]);
                acc[2][jj] = fmaf(a2, w, acc[2][jj]);
                acc[3][jj] = fmaf(a3, w, acc[3][jj]);
            }
        }
    }
    __syncthreads();

    // ---- epilogue overlays (xs/wch dead) ----
    float* hsem = smem;                    // [32][132]
    float* WsT  = smem + 4224;             // [50][132] (Wseg transposed)
    float* segl = smem + 10824;            // [32][52]

    for (int i = t; i < GG * 128; i += 256) {     // stage Wseg^T
        int g = i >> 7, d = i & 127;
        WsT[g * 132 + d] = Wseg[d * GG + g];
    }

    #pragma unroll
    for (int pp = 0; pp < 4; ++pp) {
        int p = tp * 4 + pp;
        float vv[12];
        #pragma unroll
        for (int jj = 0; jj < 12; ++jj) {
            int j = tj * 12 + jj;
            float bb = (j < 128) ? bsim[j] : (j < 256 ? bsem[j - 128] : bconf[j - 256]);
            vv[jj] = acc[pp][jj] + bb;
        }
        float rsq = 0.f;                           // norm of ROUNDED bf16 sim values
        #pragma unroll
        for (int jj = 0; jj < 12; ++jj) {
            int j = tj * 12 + jj;
            if (j < 128) {
                float f = bf16f((short)bf16b(vv[jj]));
                rsq = fmaf(f, f, rsq);
            }
        }
        if (tj <= 10) atomicAdd(&rns[p], rsq);
        #pragma unroll
        for (int jj = 0; jj < 12; jj += 2) {       // sim -> bf16 pairs to global ws
            int j = tj * 12 + jj;
            if (j < 128)
                fsimu[(size_t)(pbase + p) * 64 + (j >> 1)] =
                    bf16b(vv[jj]) | (bf16b(vv[jj + 1]) << 16);
        }
        #pragma unroll
        for (int jj = 0; jj < 12; ++jj) {          // sem -> LDS
            int j = tj * 12 + jj;
            if (j >= 128 && j < 256) hsem[p * 132 + (j - 128)] = vv[jj];
        }
        float c = 0.f;                              // conf partial dot with Wcl
        #pragma unroll
        for (int jj = 0; jj < 12; ++jj) {
            int j = tj * 12 + jj;
            if (j >= 256) c = fmaf(vv[jj], Wcl[j - 256], c);
        }
        if (tj >= 21) atomicAdd(&confl[p], c);
    }
    __syncthreads();

    for (int i = t; i < PB * GG; i += 256) {        // stage 2: seg logits
        int p = i / GG, g = i - p * GG;
        const float4* hp = (const float4*)&hsem[p * 132];
        const float4* wp = (const float4*)&WsT[g * 132];
        float a = bseg[g];
        #pragma unroll 8
        for (int d = 0; d < 32; ++d) {
            float4 h = hp[d], w = wp[d];
            a = fmaf(h.x, w.x, a); a = fmaf(h.y, w.y, a);
            a = fmaf(h.z, w.z, a); a = fmaf(h.w, w.w, a);
        }
        segl[p * 52 + g] = a;
    }
    __syncthreads();

    if (t < PB) {
        int p = t;
        float mx = -1e30f;
        for (int g = 0; g < GG; ++g) mx = fmaxf(mx, segl[p * 52 + g]);
        float s = 0.f;
        for (int g = 0; g < GG; ++g) s += __expf(segl[p * 52 + g] - mx);
        mxs[p] = mx; sms[p] = 1.f / s;
        float cl = confl[p] + bcl[0];
        out4[pbase + p] = cl;
        out3[pbase + p] = 1.f / (1.f + __expf(-cl));
        rnorm[pbase + p] = rns[p];
    }
    __syncthreads();

    for (int i = t; i < PB * GG; i += 256) {
        int p = i / GG, g = i - p * GG;
        float l = segl[p * 52 + g];
        size_t o = (size_t)(pbase + p) * GG + g;
        out1[o] = l;
        out0[o] = __expf(l - mxs[p]) * sms[p];
    }
}

// ------------- k_simmat: out2 = relu(10*(r_i - 2*F F^T + r_j)) -----------------------------
// symmetric: only upper-triangle tile pairs launched; each block writes tile (I,J) with
// scalar stores and tile (J,I) with f32x4 stores (fragment rows -> mirrored contiguous cols)
typedef short short8 __attribute__((ext_vector_type(8)));
typedef float f32x4 __attribute__((ext_vector_type(4)));

__global__ __launch_bounds__(256) void k_simmat(
    const short* __restrict__ fs, const float* __restrict__ rn, float* __restrict__ out2)
{
    int t = threadIdx.x;
    int lane = t & 63, wv = t >> 6;
    int b = blockIdx.y;

    // decode upper-triangle pair: p = tj*(tj+1)/2 + ti, ti <= tj
    int p = blockIdx.x;
    int tj = (int)((sqrtf((float)(8 * p + 1)) - 1.f) * 0.5f);
    while ((tj + 1) * (tj + 2) / 2 <= p) ++tj;
    while (tj * (tj + 1) / 2 > p) --tj;
    int ti = p - tj * (tj + 1) / 2;

    int I = ti * 128 + (wv >> 1) * 64;
    int J = tj * 128 + (wv & 1) * 64;
    int rowl = lane & 15, quad = lane >> 4;

    const short8* F = (const short8*)(fs + (size_t)b * NN * 128);  // row = 16 short8
    const float* rb = rn + b * NN;

    f32x4 acc[4][4];
    #pragma unroll
    for (int r = 0; r < 4; ++r)
        #pragma unroll
        for (int c = 0; c < 4; ++c) { f32x4 z = {0.f,0.f,0.f,0.f}; acc[r][c] = z; }

    #pragma unroll
    for (int s = 0; s < 4; ++s) {
        short8 av[4], bv[4];
        #pragma unroll
        for (int r = 0; r < 4; ++r)
            av[r] = F[(size_t)(I + r * 16 + rowl) * 16 + s * 4 + quad];
        #pragma unroll
        for (int c = 0; c < 4; ++c)
            bv[c] = F[(size_t)(J + c * 16 + rowl) * 16 + s * 4 + quad];
        #pragma unroll
        for (int r = 0; r < 4; ++r)
            #pragma unroll
            for (int c = 0; c < 4; ++c)
                acc[r][c] = __builtin_amdgcn_mfma_f32_16x16x32_bf16(av[r], bv[c], acc[r][c], 0, 0, 0);
    }

    // precomputed norms: rI4[r][e] = r(I + r*16 + quad*4 + e), rJs[c] = r(J + c*16 + rowl)
    f32x4 rI4[4];
    float rJs[4];
    #pragma unroll
    for (int r = 0; r < 4; ++r)
        rI4[r] = *(const f32x4*)&rb[I + r * 16 + quad * 4];
    #pragma unroll
    for (int c = 0; c < 4; ++c)
        rJs[c] = rb[J + c * 16 + rowl];

    // relu'd D values in place: acc[r][c][e] = relu(10*(r_row + r_col) - 20*gram)
    #pragma unroll
    for (int r = 0; r < 4; ++r)
        #pragma unroll
        for (int c = 0; c < 4; ++c) {
            f32x4 v = acc[r][c];
            float rj = rJs[c];
            f32x4 o;
            #pragma unroll
            for (int e = 0; e < 4; ++e)
                o[e] = fmaxf(10.f * (rI4[r][e] + rj) - 20.f * v[e], 0.f);
            acc[r][c] = o;
        }

    float* ob = out2 + (size_t)b * NN * NN;

    // tile (I,J): row = I + r*16 + quad*4 + e, col = J + c*16 + rowl (scalar, NT)
    #pragma unroll
    for (int r = 0; r < 4; ++r) {
        int rbase = I + r * 16 + quad * 4;
        #pragma unroll
        for (int c = 0; c < 4; ++c) {
            int col = J + c * 16 + rowl;
            f32x4 v = acc[r][c];
            #pragma unroll
            for (int e = 0; e < 4; ++e)
                __builtin_nontemporal_store(v[e], &ob[(size_t)(rbase + e) * NN + col]);
        }
    }

    // tile (J,I) by symmetry: row = J + c*16 + rowl, cols I + r*16 + quad*4 .. +3 (f32x4, NT)
    if (ti != tj) {
        #pragma unroll
        for (int c = 0; c < 4; ++c) {
            size_t rowoff = (size_t)(J + c * 16 + rowl) * NN;
            #pragma unroll
            for (int r = 0; r < 4; ++r)
                __builtin_nontemporal_store(acc[r][c],
                    (f32x4*)&ob[rowoff + (I + r * 16 + quad * 4)]);
        }
    }
}

extern "C" void kernel_launch(void* const* d_in, const int* in_sizes, int n_in,
                              void* d_out, int out_size, void* d_ws, size_t ws_size,
                              hipStream_t stream)
{
    const float* x     = (const float*)d_in[0];
    const float* Wsem  = (const float*)d_in[1];
    const float* bsem  = (const float*)d_in[2];
    const float* Wseg  = (const float*)d_in[3];
    const float* bseg  = (const float*)d_in[4];
    const float* Wsim  = (const float*)d_in[5];
    const float* bsim  = (const float*)d_in[6];
    const float* Wconf = (const float*)d_in[7];
    const float* bconf = (const float*)d_in[8];
    const float* Wcl   = (const float*)d_in[9];
    const float* bcl   = (const float*)d_in[10];

    // scratch: Fsim bf16 (4 MiB) + row norms fp32 (64 KiB)
    const size_t FSIM_BYTES = (size_t)4 * NN * 128 * 2;
    if (ws_size < FSIM_BYTES + (size_t)4 * NN * sizeof(float)) return;
    unsigned* fsim = (unsigned*)d_ws;
    float* rnorm = (float*)((char*)d_ws + FSIM_BYTES);

    float* out  = (float*)d_out;
    float* out0 = out;
    float* out1 = out + O_OUT1;
    float* out2 = out + O_OUT2;
    float* out3 = out + O_OUT3;
    float* out4 = out + O_OUT4;

    hipLaunchKernelGGL(k_proj, dim3(512), dim3(256), 0, stream,
                       x, Wsem, bsem, Wseg, bseg, Wsim, bsim, Wconf, bconf, Wcl, bcl,
                       fsim, rnorm, out0, out1, out3, out4);
    hipLaunchKernelGGL(k_simmat, dim3(528, 4, 1), dim3(256), 0, stream,
                       (const short*)fsim, rnorm, out2);
}

// Round 3
// 359.194 us; speedup vs baseline: 1.1767x; 1.1767x over previous
//
#include <hip/hip_runtime.h>
#include <cstdint>
#include <cstddef>

#define NN 4096
#define CC 256
#define GG 50

#define O_OUT1 819200
#define O_OUT2 1638400
#define O_OUT3 68747264
#define O_OUT4 68763648

typedef _Float16 half8 __attribute__((ext_vector_type(8)));
typedef float f32x4 __attribute__((ext_vector_type(4)));
typedef short short8 __attribute__((ext_vector_type(8)));

__device__ __forceinline__ unsigned bf16b(float f) {
    unsigned u = __float_as_uint(f);
    return (u + 0x7FFFu + ((u >> 16) & 1u)) >> 16;   // RNE f32->bf16
}
__device__ __forceinline__ float bf16f(short s) {
    return __uint_as_float(((unsigned)(unsigned short)s) << 16);
}

// ------------- k_proj v2: fp16 MFMA for the 3 projections (operand-swapped: D[j][pt]) ------
// 256 blocks x 256 thr (4 waves). Block owns 64 points; wave wv owns j-frags wv*6..wv*6+5.
// No LDS / no barriers in main loop. Epilogue: sim->bf16 fsim + rnorm, sem->LDS->seg MFMA
// ->in-register softmax, conf dot -> sigmoid.
__global__ __launch_bounds__(256) void k_proj(
    const float* __restrict__ x,
    const float* __restrict__ Wsem, const float* __restrict__ bsem,
    const float* __restrict__ Wseg, const float* __restrict__ bseg,
    const float* __restrict__ Wsim, const float* __restrict__ bsim,
    const float* __restrict__ Wconf, const float* __restrict__ bconf,
    const float* __restrict__ Wcl, const float* __restrict__ bcl,
    unsigned* __restrict__ fsimu, float* __restrict__ rnorm,
    float* __restrict__ out0, float* __restrict__ out1,
    float* __restrict__ out3, float* __restrict__ out4)
{
    __shared__ float hsem[64 * 132];       // Fsem staging [pt][d], stride 132
    __shared__ float confl[64], rns[64];

    int t = threadIdx.x;
    int lane = t & 63, wv = t >> 6;
    int rowl = lane & 15, quad = lane >> 4;
    int pbase = blockIdx.x * 64;

    if (t < 64) { confl[t] = 0.f; rns[t] = 0.f; }

    // A-operand: W^T — lane(rowl,quad) covers A[j = jfg*16+rowl][c = kc*32+quad*8+e]
    const float* wcol[6];
    #pragma unroll
    for (int jf = 0; jf < 6; ++jf) {
        int j384 = (wv * 6 + jf) * 16 + rowl;
        const float* m = (j384 < 128) ? Wsim : (j384 < 256) ? Wsem : Wconf;
        wcol[jf] = m + (j384 & 127);
    }
    // B-operand: x — lane(rowl,quad) covers B[c][pt = pf*16+rowl]
    const float* xrow[4];
    #pragma unroll
    for (int pf = 0; pf < 4; ++pf)
        xrow[pf] = x + (size_t)(pbase + pf * 16 + rowl) * CC;

    f32x4 acc[6][4];
    #pragma unroll
    for (int jf = 0; jf < 6; ++jf)
        #pragma unroll
        for (int pf = 0; pf < 4; ++pf) { f32x4 z = {0.f,0.f,0.f,0.f}; acc[jf][pf] = z; }

    #pragma unroll 2
    for (int kc = 0; kc < 8; ++kc) {
        half8 A[6];
        #pragma unroll
        for (int jf = 0; jf < 6; ++jf) {
            const float* wp = wcol[jf] + (size_t)(kc * 32 + quad * 8) * 128;
            #pragma unroll
            for (int e = 0; e < 8; ++e) A[jf][e] = (_Float16)wp[(size_t)e * 128];
        }
        half8 Bv[4];
        #pragma unroll
        for (int pf = 0; pf < 4; ++pf) {
            const float* xp = xrow[pf] + kc * 32 + quad * 8;
            float4 x0 = *(const float4*)xp;
            float4 x1 = *(const float4*)(xp + 4);
            Bv[pf][0] = (_Float16)x0.x; Bv[pf][1] = (_Float16)x0.y;
            Bv[pf][2] = (_Float16)x0.z; Bv[pf][3] = (_Float16)x0.w;
            Bv[pf][4] = (_Float16)x1.x; Bv[pf][5] = (_Float16)x1.y;
            Bv[pf][6] = (_Float16)x1.z; Bv[pf][7] = (_Float16)x1.w;
        }
        #pragma unroll
        for (int pf = 0; pf < 4; ++pf)
            #pragma unroll
            for (int jf = 0; jf < 6; ++jf)
                acc[jf][pf] = __builtin_amdgcn_mfma_f32_16x16x32_f16(A[jf], Bv[pf], acc[jf][pf], 0, 0, 0);
    }

    __syncthreads();   // confl/rns init visible to all; hsem region free

    // ---- epilogue part 1: distribute D[j][pt] (j = jfg*16 + quad*4 + e, pt = pf*16 + rowl) ----
    float rsum[4] = {0.f,0.f,0.f,0.f};
    float csum[4] = {0.f,0.f,0.f,0.f};
    bool hasSim = (wv * 6 < 8);            // waves 0,1
    bool hasConf = (wv * 6 + 5 >= 16);     // waves 2,3

    #pragma unroll
    for (int jf = 0; jf < 6; ++jf) {
        int jfg = wv * 6 + jf;
        int j0 = jfg * 16 + quad * 4;
        const float* barr = (j0 < 128) ? (bsim + j0)
                          : (j0 < 256) ? (bsem + (j0 - 128)) : (bconf + (j0 - 256));
        float4 b4 = *(const float4*)barr;
        if (jfg < 8) {                                  // ---- sim -> bf16 fsim + rnorm ----
            #pragma unroll
            for (int pf = 0; pf < 4; ++pf) {
                int pt = pf * 16 + rowl;
                f32x4 v = acc[jf][pf];
                unsigned p0 = bf16b(v[0] + b4.x) | (bf16b(v[1] + b4.y) << 16);
                unsigned p1 = bf16b(v[2] + b4.z) | (bf16b(v[3] + b4.w) << 16);
                *(uint2*)&fsimu[(size_t)(pbase + pt) * 64 + jfg * 8 + quad * 2] = make_uint2(p0, p1);
                float f0 = bf16f((short)(p0 & 0xFFFF)), f1 = bf16f((short)(p0 >> 16));
                float f2 = bf16f((short)(p1 & 0xFFFF)), f3 = bf16f((short)(p1 >> 16));
                rsum[pf] += f0*f0 + f1*f1 + f2*f2 + f3*f3;
            }
        } else if (jfg < 16) {                          // ---- sem -> LDS ----
            #pragma unroll
            for (int pf = 0; pf < 4; ++pf) {
                int pt = pf * 16 + rowl;
                f32x4 v = acc[jf][pf];
                f32x4 o;
                o[0] = v[0] + b4.x; o[1] = v[1] + b4.y; o[2] = v[2] + b4.z; o[3] = v[3] + b4.w;
                *(f32x4*)&hsem[pt * 132 + (jfg - 8) * 16 + quad * 4] = o;
            }
        } else {                                        // ---- conf partial dot ----
            float4 w4 = *(const float4*)&Wcl[(jfg - 16) * 16 + quad * 4];
            #pragma unroll
            for (int pf = 0; pf < 4; ++pf) {
                f32x4 v = acc[jf][pf];
                csum[pf] += (v[0] + b4.x) * w4.x + (v[1] + b4.y) * w4.y
                          + (v[2] + b4.z) * w4.z + (v[3] + b4.w) * w4.w;
            }
        }
    }
    if (hasSim) {
        #pragma unroll
        for (int pf = 0; pf < 4; ++pf) atomicAdd(&rns[pf * 16 + rowl], rsum[pf]);
    }
    if (hasConf) {
        #pragma unroll
        for (int pf = 0; pf < 4; ++pf) atomicAdd(&confl[pf * 16 + rowl], csum[pf]);
    }
    __syncthreads();

    // ---- conf sigmoid + rnorm writeback ----
    if (t < 64) {
        float cl = confl[t] + bcl[0];
        out4[pbase + t] = cl;
        out3[pbase + t] = 1.f / (1.f + __expf(-cl));
        rnorm[pbase + t] = rns[t];
    }

    // ---- seg logits via MFMA: D[g][pt] = Wseg^T (g x 128) @ Fsem^T (128 x pt) ----
    // wave wv handles pts wv*16 .. wv*16+15
    half8 As[4][4];
    #pragma unroll
    for (int gf = 0; gf < 4; ++gf) {
        int gg = gf * 16 + rowl;
        #pragma unroll
        for (int k2 = 0; k2 < 4; ++k2)
            #pragma unroll
            for (int e = 0; e < 8; ++e) {
                int d = k2 * 32 + quad * 8 + e;
                As[gf][k2][e] = (gg < GG) ? (_Float16)Wseg[(size_t)d * GG + gg] : (_Float16)0.f;
            }
    }
    f32x4 sacc[4];
    #pragma unroll
    for (int gf = 0; gf < 4; ++gf) { f32x4 z = {0.f,0.f,0.f,0.f}; sacc[gf] = z; }
    #pragma unroll
    for (int k2 = 0; k2 < 4; ++k2) {
        const float* hp = &hsem[(wv * 16 + rowl) * 132 + k2 * 32 + quad * 8];
        half8 Bh;
        #pragma unroll
        for (int e = 0; e < 8; ++e) Bh[e] = (_Float16)hp[e];
        #pragma unroll
        for (int gf = 0; gf < 4; ++gf)
            sacc[gf] = __builtin_amdgcn_mfma_f32_16x16x32_f16(As[gf][k2], Bh, sacc[gf], 0, 0, 0);
    }

    // per-pt softmax across the 4 quad-lanes holding this pt's g values
    float l[4][4];
    float mx = -1e30f;
    #pragma unroll
    for (int gf = 0; gf < 4; ++gf)
        #pragma unroll
        for (int e = 0; e < 4; ++e) {
            int g = gf * 16 + quad * 4 + e;
            float lv = (g < GG) ? sacc[gf][e] + bseg[g] : -1e30f;
            l[gf][e] = lv;
            mx = fmaxf(mx, lv);
        }
    mx = fmaxf(mx, __shfl_xor(mx, 16));
    mx = fmaxf(mx, __shfl_xor(mx, 32));
    float s = 0.f;
    #pragma unroll
    for (int gf = 0; gf < 4; ++gf)
        #pragma unroll
        for (int e = 0; e < 4; ++e) {
            int g = gf * 16 + quad * 4 + e;
            if (g < GG) s += __expf(l[gf][e] - mx);
        }
    s += __shfl_xor(s, 16);
    s += __shfl_xor(s, 32);
    float inv = 1.f / s;

    size_t orow = (size_t)(pbase + wv * 16 + rowl) * GG;
    #pragma unroll
    for (int gf = 0; gf < 4; ++gf)
        #pragma unroll
        for (int e = 0; e < 4; ++e) {
            int g = gf * 16 + quad * 4 + e;
            if (g < GG) {
                out1[orow + g] = l[gf][e];
                out0[orow + g] = __expf(l[gf][e] - mx) * inv;
            }
        }
}

// ------------- k_simmat: out2 = relu(10*(r_i - 2*F F^T + r_j)) -----------------------------
// symmetric: only upper-triangle tile pairs launched; each block writes tile (I,J) with
// scalar stores and tile (J,I) with f32x4 stores (fragment rows -> mirrored contiguous cols)
__global__ __launch_bounds__(256) void k_simmat(
    const short* __restrict__ fs, const float* __restrict__ rn, float* __restrict__ out2)
{
    int t = threadIdx.x;
    int lane = t & 63, wv = t >> 6;
    int b = blockIdx.y;

    // decode upper-triangle pair: p = tj*(tj+1)/2 + ti, ti <= tj
    int p = blockIdx.x;
    int tj = (int)((sqrtf((float)(8 * p + 1)) - 1.f) * 0.5f);
    while ((tj + 1) * (tj + 2) / 2 <= p) ++tj;
    while (tj * (tj + 1) / 2 > p) --tj;
    int ti = p - tj * (tj + 1) / 2;

    int I = ti * 128 + (wv >> 1) * 64;
    int J = tj * 128 + (wv & 1) * 64;
    int rowl = lane & 15, quad = lane >> 4;

    const short8* F = (const short8*)(fs + (size_t)b * NN * 128);  // row = 16 short8
    const float* rb = rn + b * NN;

    f32x4 acc[4][4];
    #pragma unroll
    for (int r = 0; r < 4; ++r)
        #pragma unroll
        for (int c = 0; c < 4; ++c) { f32x4 z = {0.f,0.f,0.f,0.f}; acc[r][c] = z; }

    #pragma unroll
    for (int s = 0; s < 4; ++s) {
        short8 av[4], bv[4];
        #pragma unroll
        for (int r = 0; r < 4; ++r)
            av[r] = F[(size_t)(I + r * 16 + rowl) * 16 + s * 4 + quad];
        #pragma unroll
        for (int c = 0; c < 4; ++c)
            bv[c] = F[(size_t)(J + c * 16 + rowl) * 16 + s * 4 + quad];
        #pragma unroll
        for (int r = 0; r < 4; ++r)
            #pragma unroll
            for (int c = 0; c < 4; ++c)
                acc[r][c] = __builtin_amdgcn_mfma_f32_16x16x32_bf16(av[r], bv[c], acc[r][c], 0, 0, 0);
    }

    // precomputed norms: rI4[r][e] = r(I + r*16 + quad*4 + e), rJs[c] = r(J + c*16 + rowl)
    f32x4 rI4[4];
    float rJs[4];
    #pragma unroll
    for (int r = 0; r < 4; ++r)
        rI4[r] = *(const f32x4*)&rb[I + r * 16 + quad * 4];
    #pragma unroll
    for (int c = 0; c < 4; ++c)
        rJs[c] = rb[J + c * 16 + rowl];

    // relu'd D values in place
    #pragma unroll
    for (int r = 0; r < 4; ++r)
        #pragma unroll
        for (int c = 0; c < 4; ++c) {
            f32x4 v = acc[r][c];
            float rj = rJs[c];
            f32x4 o;
            #pragma unroll
            for (int e = 0; e < 4; ++e)
                o[e] = fmaxf(10.f * (rI4[r][e] + rj) - 20.f * v[e], 0.f);
            acc[r][c] = o;
        }

    float* ob = out2 + (size_t)b * NN * NN;

    // tile (I,J): row = I + r*16 + quad*4 + e, col = J + c*16 + rowl (scalar, NT)
    #pragma unroll
    for (int r = 0; r < 4; ++r) {
        int rbase = I + r * 16 + quad * 4;
        #pragma unroll
        for (int c = 0; c < 4; ++c) {
            int col = J + c * 16 + rowl;
            f32x4 v = acc[r][c];
            #pragma unroll
            for (int e = 0; e < 4; ++e)
                __builtin_nontemporal_store(v[e], &ob[(size_t)(rbase + e) * NN + col]);
        }
    }

    // tile (J,I) by symmetry: row = J + c*16 + rowl, cols I + r*16 + quad*4 .. +3 (f32x4, NT)
    if (ti != tj) {
        #pragma unroll
        for (int c = 0; c < 4; ++c) {
            size_t rowoff = (size_t)(J + c * 16 + rowl) * NN;
            #pragma unroll
            for (int r = 0; r < 4; ++r)
                __builtin_nontemporal_store(acc[r][c],
                    (f32x4*)&ob[rowoff + (I + r * 16 + quad * 4)]);
        }
    }
}

extern "C" void kernel_launch(void* const* d_in, const int* in_sizes, int n_in,
                              void* d_out, int out_size, void* d_ws, size_t ws_size,
                              hipStream_t stream)
{
    const float* x     = (const float*)d_in[0];
    const float* Wsem  = (const float*)d_in[1];
    const float* bsem  = (const float*)d_in[2];
    const float* Wseg  = (const float*)d_in[3];
    const float* bseg  = (const float*)d_in[4];
    const float* Wsim  = (const float*)d_in[5];
    const float* bsim  = (const float*)d_in[6];
    const float* Wconf = (const float*)d_in[7];
    const float* bconf = (const float*)d_in[8];
    const float* Wcl   = (const float*)d_in[9];
    const float* bcl   = (const float*)d_in[10];

    // scratch: Fsim bf16 (4 MiB) + row norms fp32 (64 KiB)
    const size_t FSIM_BYTES = (size_t)4 * NN * 128 * 2;
    if (ws_size < FSIM_BYTES + (size_t)4 * NN * sizeof(float)) return;
    unsigned* fsim = (unsigned*)d_ws;
    float* rnorm = (float*)((char*)d_ws + FSIM_BYTES);

    float* out  = (float*)d_out;
    float* out0 = out;
    float* out1 = out + O_OUT1;
    float* out2 = out + O_OUT2;
    float* out3 = out + O_OUT3;
    float* out4 = out + O_OUT4;

    hipLaunchKernelGGL(k_proj, dim3(256), dim3(256), 0, stream,
                       x, Wsem, bsem, Wseg, bseg, Wsim, bsim, Wconf, bconf, Wcl, bcl,
                       fsim, rnorm, out0, out1, out3, out4);
    hipLaunchKernelGGL(k_simmat, dim3(528, 4, 1), dim3(256), 0, stream,
                       (const short*)fsim, rnorm, out2);
}